// Round 5
// baseline (1133.486 us; speedup 1.0000x reference)
//
#include <hip/hip_runtime.h>
#include <hip/hip_bf16.h>
#include <cstdint>
#include <cstddef>

// Problem dims (fixed by setup_inputs)
#define TDIM 2048
#define HDIM 4096
#define MDIM 14336

typedef __attribute__((ext_vector_type(8))) __bf16 bf16x8;
typedef __attribute__((ext_vector_type(4))) float f32x4;

__device__ __constant__ float NF4_LUT[16] = {
    -1.0f, -0.6961928009986877f, -0.5250730514526367f, -0.39491748809814453f,
    -0.28444138169288635f, -0.18477343022823334f, -0.09105003625154495f, 0.0f,
    0.07958029955625534f, 0.16093020141124725f, 0.24611230194568634f,
    0.33791524171829224f, 0.44070982933044434f, 0.5626170039176941f,
    0.7229568362236023f, 1.0f};

__device__ __forceinline__ void g2l16(const void* g, void* l) {
  __builtin_amdgcn_global_load_lds(
      (const __attribute__((address_space(1))) unsigned int*)g,
      (__attribute__((address_space(3))) unsigned int*)l, 16, 0, 0);
}

// ------------------------------------------------------------ x f32 -> bf16
__global__ __launch_bounds__(256) void f32_to_bf16_k(
    const float* __restrict__ in, __hip_bfloat16* __restrict__ out, int n8) {
  for (int i = blockIdx.x * 256 + threadIdx.x; i < n8; i += gridDim.x * 256) {
    const float4* p = (const float4*)(in + (size_t)i * 8);
    float4 a = p[0], b = p[1];
    union { __hip_bfloat16 h[8]; int4 v; } u;
    u.h[0] = __float2bfloat16(a.x);
    u.h[1] = __float2bfloat16(a.y);
    u.h[2] = __float2bfloat16(a.z);
    u.h[3] = __float2bfloat16(a.w);
    u.h[4] = __float2bfloat16(b.x);
    u.h[5] = __float2bfloat16(b.y);
    u.h[6] = __float2bfloat16(b.z);
    u.h[7] = __float2bfloat16(b.w);
    *(int4*)(out + (size_t)i * 8) = u.v;
  }
}

// --------------------------------------------------- NF4 dequant -> bf16 W
__global__ __launch_bounds__(256) void dequant_nf4_k(
    const int* __restrict__ codes, const float* __restrict__ absmax,
    __hip_bfloat16* __restrict__ W, int K) {
  __shared__ float lut[16];
  if (threadIdx.x < 16) lut[threadIdx.x] = NF4_LUT[threadIdx.x];
  __syncthreads();
  const int row = blockIdx.x;
  const int K8 = K >> 3;
  const size_t rbase = (size_t)row * K;
  for (int c8 = threadIdx.x; c8 < K8; c8 += 256) {
    const int col = c8 << 3;
    const float am = absmax[(size_t)row * (K >> 6) + (col >> 6)];
    const int4* cp = (const int4*)(codes + rbase + col);
    int4 ca = cp[0], cb = cp[1];
    union { __hip_bfloat16 h[8]; int4 v; } u;
    u.h[0] = __float2bfloat16(lut[ca.x & 15] * am);
    u.h[1] = __float2bfloat16(lut[ca.y & 15] * am);
    u.h[2] = __float2bfloat16(lut[ca.z & 15] * am);
    u.h[3] = __float2bfloat16(lut[ca.w & 15] * am);
    u.h[4] = __float2bfloat16(lut[cb.x & 15] * am);
    u.h[5] = __float2bfloat16(lut[cb.y & 15] * am);
    u.h[6] = __float2bfloat16(lut[cb.z & 15] * am);
    u.h[7] = __float2bfloat16(lut[cb.w & 15] * am);
    *(int4*)(W + rbase + col) = u.v;
  }
}

// ------------------------------------------------------------------- GEMM
// C[M,N] (+)= A[M,K] @ B[N,K]^T, bf16 in, f32 acc.
// 128x128 tile, BK=64, 4 waves (2x2) — round-1 proven structure.
// __launch_bounds__(256,4): 16 waves/CU = 4 blocks/CU (VGPR 64+64AGPR=128,
// LDS 32KB) — doubles TLP coverage of the per-K-tile vmcnt/barrier stall.
// Swizzle: pre-swizzled global source + swizzled LDS read (rule #21).
// EPI: 0 = store bf16; 1 = silu(G)*acc -> bf16 in-place; 2 = atomicAdd f32
template <int EPI>
__global__ __launch_bounds__(256, 4) void gemm_nt_k(
    const __hip_bfloat16* __restrict__ A, const __hip_bfloat16* __restrict__ B,
    void* __restrict__ Cv, const __hip_bfloat16* __restrict__ Gin,
    int M, int N, int Kfull, int Kloc, int ksplit) {
  __shared__ __align__(16) char sA[128 * 128];
  __shared__ __align__(16) char sB[128 * 128];

  const int tid = threadIdx.x;
  const int lane = tid & 63;
  const int wid = tid >> 6;
  const int wm = wid >> 1, wn = wid & 1;

  // bijective XCD swizzle (grid %8==0 for all our shapes), then decode
  const int nbn = N >> 7;
  const int nwg2 = (M >> 7) * nbn;
  const int G = nwg2 * ksplit;
  const int q8 = G >> 3;
  const int bid = blockIdx.x;
  const int wg = (bid & 7) * q8 + (bid >> 3);
  const int kh = wg / nwg2;
  const int rem = wg - kh * nwg2;
  const int bm = rem / nbn;
  const int bn = rem - bm * nbn;

  const size_t Kb = (size_t)Kfull * 2;  // global row stride bytes
  const size_t koffb = (size_t)kh * Kloc * 2;

  // staging geometry: wave covers rows wid*8+srow (+32 per sweep), 16B/lane
  const int srow = lane >> 3;
  const int scw = ((lane & 7) ^ srow) << 4;  // pre-swizzled source col
  const uint8_t* gA = (const uint8_t*)A +
      (size_t)(bm * 128 + wid * 8 + srow) * Kb + koffb + scw;
  const uint8_t* gB = (const uint8_t*)B +
      (size_t)(bn * 128 + wid * 8 + srow) * Kb + koffb + scw;
  char* lA = sA + wid * 1024;  // wave-uniform LDS dest bases
  char* lB = sB + wid * 1024;

  // fragment read bases (swizzled): row*128 + ((lanegrp<<4) ^ ((row&7)<<4))
  const int colsw = (((lane >> 4) << 4) ^ ((lane & 7) << 4));
  const char* aRd = sA + (wm * 64 + (lane & 15)) * 128 + colsw;
  const char* bRd = sB + (wn * 64 + (lane & 15)) * 128 + colsw;

  f32x4 acc[4][4] = {};

  const int nt = Kloc >> 6;
  for (int kt = 0; kt < nt; ++kt) {
    const size_t kb = (size_t)kt * 128;
#pragma unroll
    for (int s = 0; s < 4; ++s) {  // 4 sweeps of 32 rows each
      g2l16(gA + (size_t)(s * 32) * Kb + kb, lA + s * 4096);
      g2l16(gB + (size_t)(s * 32) * Kb + kb, lB + s * 4096);
    }
    __syncthreads();
#pragma unroll
    for (int ks = 0; ks < 2; ++ks) {
      bf16x8 af[4], bv[4];
#pragma unroll
      for (int i = 0; i < 4; ++i) {
        af[i] = *(const bf16x8*)((uintptr_t)(aRd + i * 2048) ^ (ks << 6));
        bv[i] = *(const bf16x8*)((uintptr_t)(bRd + i * 2048) ^ (ks << 6));
      }
#pragma unroll
      for (int mi = 0; mi < 4; ++mi)
#pragma unroll
        for (int nj = 0; nj < 4; ++nj)
          acc[mi][nj] = __builtin_amdgcn_mfma_f32_16x16x32_bf16(
              af[mi], bv[nj], acc[mi][nj], 0, 0, 0);
    }
    __syncthreads();
  }

  // epilogue: C/D frag layout col=lane&15, row=(lane>>4)*4+r
  const int row0 = bm * 128 + wm * 64 + ((lane >> 4) << 2);
  const int col0 = bn * 128 + wn * 64 + (lane & 15);
#pragma unroll
  for (int mi = 0; mi < 4; ++mi) {
#pragma unroll
    for (int nj = 0; nj < 4; ++nj) {
#pragma unroll
      for (int r = 0; r < 4; ++r) {
        const size_t idx =
            (size_t)(row0 + mi * 16 + r) * N + (col0 + nj * 16);
        const float v = acc[mi][nj][r];
        if (EPI == 0) {
          ((__hip_bfloat16*)Cv)[idx] = __float2bfloat16(v);
        } else if (EPI == 1) {
          const float g = __bfloat162float(Gin[idx]);
          ((__hip_bfloat16*)Cv)[idx] =
              __float2bfloat16(g / (1.0f + __expf(-g)) * v);
        } else {
          atomicAdd(&((float*)Cv)[idx], v);
        }
      }
    }
  }
}

// ---------------------------------------------------------------- launcher
extern "C" void kernel_launch(void* const* d_in, const int* in_sizes, int n_in,
                              void* d_out, int out_size, void* d_ws,
                              size_t ws_size, hipStream_t stream) {
  const float* x = (const float*)d_in[0];
  const int* gate_codes = (const int*)d_in[1];
  const float* gate_absmax = (const float*)d_in[2];
  const int* up_codes = (const int*)d_in[3];
  const float* up_absmax = (const float*)d_in[4];
  const int* down_codes = (const int*)d_in[5];
  const float* down_absmax = (const float*)d_in[6];

  char* ws = (char*)d_ws;
  __hip_bfloat16* xb = (__hip_bfloat16*)ws;                              // 16 MB
  __hip_bfloat16* Wb = (__hip_bfloat16*)(ws + (size_t)TDIM * HDIM * 2);  // 112 MB
  __hip_bfloat16* Hb = (__hip_bfloat16*)(ws + (size_t)TDIM * HDIM * 2 +
                                         (size_t)MDIM * HDIM * 2);       // 56 MB

  // down GEMM accumulates atomically -> zero d_out each call
  hipMemsetAsync(d_out, 0, (size_t)TDIM * HDIM * 4, stream);

  f32_to_bf16_k<<<2048, 256, 0, stream>>>(x, xb, (TDIM * HDIM) / 8);

  // gate: grid 16 x 112 = 1792
  dequant_nf4_k<<<MDIM, 256, 0, stream>>>(gate_codes, gate_absmax, Wb, HDIM);
  gemm_nt_k<0><<<(TDIM / 128) * (MDIM / 128), 256, 0, stream>>>(
      xb, Wb, Hb, nullptr, TDIM, MDIM, HDIM, HDIM, 1);
  // up + swiglu
  dequant_nf4_k<<<MDIM, 256, 0, stream>>>(up_codes, up_absmax, Wb, HDIM);
  gemm_nt_k<1><<<(TDIM / 128) * (MDIM / 128), 256, 0, stream>>>(
      xb, Wb, Hb, Hb, TDIM, MDIM, HDIM, HDIM, 1);
  // down, split-K=2: grid 2 x 16 x 32 = 1024 (4 blocks/CU residency)
  dequant_nf4_k<<<HDIM, 256, 0, stream>>>(down_codes, down_absmax, Wb, MDIM);
  gemm_nt_k<2><<<2 * (TDIM / 128) * (HDIM / 128), 256, 0, stream>>>(
      Hb, Wb, (float*)d_out, nullptr, TDIM, HDIM, MDIM, MDIM / 2, 2);
}